// Round 1
// baseline (621.099 us; speedup 1.0000x reference)
//
#include <hip/hip_runtime.h>
#include <hip/hip_bf16.h>

#define NROWS 8192
#define DIM   512
#define KSEL  20
#define PANEL 1024
#define NPANELS (NROWS / PANEL)

typedef unsigned int u32;
typedef short bf16x8 __attribute__((ext_vector_type(8)));
typedef float f32x4 __attribute__((ext_vector_type(4)));

typedef const void __attribute__((address_space(1))) as1_void;
typedef void __attribute__((address_space(3))) as3_void;

__device__ __forceinline__ void async_ld16(const ushort* g, ushort* l) {
    __builtin_amdgcn_global_load_lds((as1_void*)g, (as3_void*)l, 16, 0, 0);
}

// round-to-nearest-even f32 -> bf16 bits
__device__ __forceinline__ ushort f2bf(float f) {
    u32 u = __float_as_uint(f);
    return (ushort)((u + 0x7FFFu + ((u >> 16) & 1u)) >> 16);
}

// ---------------- normalize: fp32 rows -> unit-norm bf16 rows ----------------
__global__ __launch_bounds__(256) void k_norm(const float* __restrict__ x,
                                              ushort* __restrict__ xn) {
    int lane = threadIdx.x & 63;
    int wv   = threadIdx.x >> 6;
    int row  = blockIdx.x * 4 + wv;
    const float4* xr = (const float4*)(x + (size_t)row * DIM);
    float4 a = xr[2 * lane];
    float4 b = xr[2 * lane + 1];
    float ss = a.x*a.x + a.y*a.y + a.z*a.z + a.w*a.w
             + b.x*b.x + b.y*b.y + b.z*b.z + b.w*b.w;
    #pragma unroll
    for (int off = 32; off; off >>= 1) ss += __shfl_xor(ss, off);
    float sc = 1.0f / fmaxf(sqrtf(ss), 1e-12f);
    float v[8] = {a.x*sc, a.y*sc, a.z*sc, a.w*sc, b.x*sc, b.y*sc, b.z*sc, b.w*sc};
    union { ushort u[8]; uint4 q; } o;
    #pragma unroll
    for (int i = 0; i < 8; ++i) o.u[i] = f2bf(v[i]);
    *(uint4*)(xn + (size_t)row * DIM + lane * 8) = o.q;
}

// ---------------- GEMM: cos panel = Xn[panel] * Xn^T, bf16 out ----------------
// 128x128 tile, 4 waves (2x2), each wave 4x4 subtiles of 16x16x32 bf16 MFMA.
// LDS: [row][8 chunks of 16B], chunk slot XOR-swizzled by (row&7) so that
// global_load_lds (uniform base + lane*16) works AND frag ds_read_b128 is
// conflict-free (each consecutive-8-lane cluster hits all 8 bank groups).
__global__ __launch_bounds__(256) void k_gemm(const ushort* __restrict__ xn,
                                              ushort* __restrict__ cpan,
                                              int row0) {
    __shared__ ushort lA[128 * 64];
    __shared__ ushort lB[128 * 64];
    int tid  = threadIdx.x;
    int lane = tid & 63, wv = tid >> 6;
    int wr = wv >> 1, wc = wv & 1;
    int q = lane >> 4, m = lane & 15;
    int grow0 = row0 + blockIdx.y * 128;
    int gcol0 = blockIdx.x * 128;
    f32x4 acc[4][4] = {};

    int lr = lane >> 3;   // row within 8-row group
    int lc = lane & 7;    // LDS chunk slot this lane fills
    for (int kc = 0; kc < 8; ++kc) {
        #pragma unroll
        for (int t = 0; t < 4; ++t) {
            int rb  = wv * 32 + t * 8;     // wave-uniform row base
            int r   = rb + lr;
            int fch = lc ^ (r & 7);        // which global chunk to fetch into slot lc
            async_ld16(xn + (size_t)(grow0 + r) * DIM + kc * 64 + fch * 8, &lA[rb * 64]);
            async_ld16(xn + (size_t)(gcol0 + r) * DIM + kc * 64 + fch * 8, &lB[rb * 64]);
        }
        __syncthreads();
        #pragma unroll
        for (int s = 0; s < 2; ++s) {
            bf16x8 af[4], bfr[4];
            #pragma unroll
            for (int i = 0; i < 4; ++i) {
                int ra = wr * 64 + i * 16 + m;
                af[i]  = *(const bf16x8*)&lA[ra * 64 + (((s * 4 + q) ^ (ra & 7)) * 8)];
                int rb2 = wc * 64 + i * 16 + m;
                bfr[i] = *(const bf16x8*)&lB[rb2 * 64 + (((s * 4 + q) ^ (rb2 & 7)) * 8)];
            }
            #pragma unroll
            for (int i = 0; i < 4; ++i)
                #pragma unroll
                for (int j = 0; j < 4; ++j)
                    acc[i][j] = __builtin_amdgcn_mfma_f32_16x16x32_bf16(af[i], bfr[j], acc[i][j], 0, 0, 0);
        }
        __syncthreads();
    }
    // epilogue: C/D layout col=lane&15, row=quad*4+reg (m89/m91-verified)
    #pragma unroll
    for (int i = 0; i < 4; ++i) {
        #pragma unroll
        for (int j = 0; j < 4; ++j) {
            int c = gcol0 + wc * 64 + j * 16 + m;
            #pragma unroll
            for (int reg = 0; reg < 4; ++reg) {
                int rp = blockIdx.y * 128 + wr * 64 + i * 16 + q * 4 + reg;
                cpan[(size_t)rp * NROWS + c] = f2bf(acc[i][j][reg]);
            }
        }
    }
}

// ---------------- select: wave-per-row exact top-20 + BCE ----------------
// keys: monotone-u16(bf16) so integer max == float max; self excluded as 0.
__global__ __launch_bounds__(256) void k_select(const ushort* __restrict__ cpan,
                                                const int* __restrict__ labels,
                                                int row0, float* __restrict__ acc) {
    __shared__ u32 s_surv[4][256];
    __shared__ u32 s_cnt[4];
    int lane = threadIdx.x & 63;
    int wv   = threadIdx.x >> 6;
    int prow = blockIdx.x * 4 + wv;
    int grow = row0 + prow;
    const u32* rowp = (const u32*)(cpan + (size_t)prow * NROWS);

    if (lane == 0) s_cnt[wv] = 0;
    __syncthreads();

    u32 pk[64];
    u32 lmax = 0;
    #pragma unroll
    for (int i = 0; i < 64; ++i) {
        u32 w  = rowp[i * 64 + lane];
        u32 c0 = (u32)(i * 64 + lane) * 2u;
        u32 r0 = w & 0xFFFFu, r1 = w >> 16;
        u32 k0 = r0 ^ (0x8000u + (r0 >> 15) * 0x7FFFu);  // monotone map
        u32 k1 = r1 ^ (0x8000u + (r1 >> 15) * 0x7FFFu);
        if (c0 == (u32)grow)     k0 = 0;                 // exclude self
        if (c0 + 1 == (u32)grow) k1 = 0;
        pk[i] = (k0 << 16) | k1;
        lmax = max(lmax, max(k0, k1));
    }

    // T = 20th-largest of the 64 lane maxima: valid lower bound on true 20th.
    u32 cur = lmax, T = 1;
    for (int r = 0; r < KSEL; ++r) {
        u32 w = cur;
        #pragma unroll
        for (int off = 32; off; off >>= 1) w = max(w, __shfl_xor(w, off));
        T = w;
        cur = (cur == w) ? 0u : cur;
    }
    if (T == 0) T = 1;

    // compact survivors (>= T) into LDS; expected ~25 per row
    for (int i = 0; i < 64; ++i) {
        u32 k0 = pk[i] >> 16, k1 = pk[i] & 0xFFFFu;
        u32 c0 = (u32)(i * 64 + lane) * 2u;
        if (k0 >= T) {
            u32 p = atomicAdd(&s_cnt[wv], 1u);
            if (p < 256u) s_surv[wv][p] = (k0 << 16) | c0;
        }
        if (k1 >= T) {
            u32 p = atomicAdd(&s_cnt[wv], 1u);
            if (p < 256u) s_surv[wv][p] = (k1 << 16) | (c0 + 1u);
        }
    }
    __syncthreads();
    u32 cnt = min(s_cnt[wv], 256u);
    u32 g[4];
    #pragma unroll
    for (int j = 0; j < 4; ++j) {
        u32 idx = (u32)lane + (u32)j * 64u;
        g[j] = (idx < cnt) ? s_surv[wv][idx] : 0u;
    }

    int mylab = labels[grow];
    float loss = 0.0f;
    for (int r = 0; r < KSEL; ++r) {
        u32 w = max(max(g[0], g[1]), max(g[2], g[3]));
        #pragma unroll
        for (int off = 32; off; off >>= 1) w = max(w, __shfl_xor(w, off));
        #pragma unroll
        for (int j = 0; j < 4; ++j) g[j] = (g[j] == w) ? 0u : g[j];  // col makes keys unique
        if (lane == 0) {
            u32 mono = w >> 16, col = w & 0xFFFFu;
            u32 raw  = (mono & 0x8000u) ? (mono ^ 0x8000u) : (mono ^ 0xFFFFu);
            float v  = __uint_as_float(raw << 16);
            float p  = (v + 1.0f) * 0.5f;
            bool t   = (labels[col] == mylab);
            float term = t ? fmaxf(logf(p), -100.0f) : fmaxf(log1pf(-p), -100.0f);
            loss -= term;
        }
    }
    if (lane == 0) atomicAdd(acc, loss);
}

__global__ void k_final(const float* __restrict__ acc, float* __restrict__ out) {
    out[0] = acc[0] * (1.0f / (float)(NROWS * KSEL));
}

extern "C" void kernel_launch(void* const* d_in, const int* in_sizes, int n_in,
                              void* d_out, int out_size, void* d_ws, size_t ws_size,
                              hipStream_t stream) {
    const float* batch  = (const float*)d_in[0];
    const int*   labels = (const int*)d_in[1];

    ushort* xn   = (ushort*)d_ws;                           // 8 MB
    ushort* cpan = xn + (size_t)NROWS * DIM;                // 16 MB panel
    float*  accp = (float*)(cpan + (size_t)PANEL * NROWS);  // 4 B

    hipMemsetAsync(accp, 0, sizeof(float), stream);
    k_norm<<<NROWS / 4, 256, 0, stream>>>(batch, xn);
    for (int p = 0; p < NPANELS; ++p) {
        k_gemm<<<dim3(NROWS / 128, PANEL / 128), 256, 0, stream>>>(xn, cpan, p * PANEL);
        k_select<<<PANEL / 4, 256, 0, stream>>>(cpan, labels, p * PANEL, accp);
    }
    k_final<<<1, 1, 0, stream>>>(accp, (float*)d_out);
}

// Round 2
// 275.333 us; speedup vs baseline: 2.2558x; 2.2558x over previous
//
#include <hip/hip_runtime.h>
#include <hip/hip_bf16.h>

#define NROWS 8192
#define DIM   512
#define KSEL  20
#define PANEL 1024

typedef unsigned int u32;
typedef short bf16x8 __attribute__((ext_vector_type(8)));
typedef float f32x4 __attribute__((ext_vector_type(4)));
typedef ushort u16x2 __attribute__((ext_vector_type(2)));
typedef ushort us4 __attribute__((ext_vector_type(4)));

typedef const void __attribute__((address_space(1))) as1_void;
typedef void __attribute__((address_space(3))) as3_void;

__device__ __forceinline__ void async_ld16(const ushort* g, ushort* l) {
    __builtin_amdgcn_global_load_lds((as1_void*)g, (as3_void*)l, 16, 0, 0);
}

// round-to-nearest-even f32 -> bf16 bits
__device__ __forceinline__ ushort f2bf(float f) {
    u32 u = __float_as_uint(f);
    return (ushort)((u + 0x7FFFu + ((u >> 16) & 1u)) >> 16);
}

// ---------------- normalize: fp32 rows -> unit-norm bf16 rows ----------------
__global__ __launch_bounds__(256) void k_norm(const float* __restrict__ x,
                                              ushort* __restrict__ xn) {
    int lane = threadIdx.x & 63;
    int wv   = threadIdx.x >> 6;
    int row  = blockIdx.x * 4 + wv;
    const float4* xr = (const float4*)(x + (size_t)row * DIM);
    float4 a = xr[2 * lane];
    float4 b = xr[2 * lane + 1];
    float ss = a.x*a.x + a.y*a.y + a.z*a.z + a.w*a.w
             + b.x*b.x + b.y*b.y + b.z*b.z + b.w*b.w;
    #pragma unroll
    for (int off = 32; off; off >>= 1) ss += __shfl_xor(ss, off);
    float sc = 1.0f / fmaxf(sqrtf(ss), 1e-12f);
    float v[8] = {a.x*sc, a.y*sc, a.z*sc, a.w*sc, b.x*sc, b.y*sc, b.z*sc, b.w*sc};
    union { ushort u[8]; uint4 q; } o;
    #pragma unroll
    for (int i = 0; i < 8; ++i) o.u[i] = f2bf(v[i]);
    *(uint4*)(xn + (size_t)row * DIM + lane * 8) = o.q;
}

// ---------------- GEMM: C = Xn * Xn^T (bf16 out), diag = -3.0 ----------------
// 128x128 tile, 4 waves (2x2), each wave 4x4 subtiles of 16x16x32 bf16 MFMA.
// TRI=true: blockIdx.x enumerates 2080 lower-triangle blocks (bx<=by), each
// writes its tile AND its mirrored transpose -> full symmetric C at half FLOPs.
// TRI=false: rectangular panel (fallback when ws is small), rows [row0,row0+P).
template<bool TRI>
__global__ __launch_bounds__(256) void k_gemm(const ushort* __restrict__ xn,
                                              ushort* __restrict__ C,
                                              int row0) {
    __shared__ ushort lA[128 * 64];
    __shared__ ushort lB[128 * 64];
    int tid  = threadIdx.x;
    int lane = tid & 63, wv = tid >> 6;
    int wr = wv >> 1, wc = wv & 1;
    int q = lane >> 4, m = lane & 15;
    int bx, by;
    if (TRI) {
        int t = blockIdx.x;
        by = (int)((sqrtf(8.0f * (float)t + 1.0f) - 1.0f) * 0.5f);
        while ((by + 1) * (by + 2) / 2 <= t) ++by;
        while (by * (by + 1) / 2 > t) --by;
        bx = t - by * (by + 1) / 2;          // bx <= by
    } else {
        bx = blockIdx.x; by = blockIdx.y;
    }
    int grow0 = row0 + by * 128;   // A rows (global)
    int gcol0 = bx * 128;          // B rows = C cols (global)
    f32x4 acc[4][4] = {};

    int lr = lane >> 3;   // row within 8-row group
    int lc = lane & 7;    // LDS chunk slot this lane fills
    for (int kc = 0; kc < 8; ++kc) {
        #pragma unroll
        for (int t = 0; t < 4; ++t) {
            int rb  = wv * 32 + t * 8;     // wave-uniform row base
            int r   = rb + lr;
            int fch = lc ^ (r & 7);        // XOR chunk swizzle (bank-conflict-free)
            async_ld16(xn + (size_t)(grow0 + r) * DIM + kc * 64 + fch * 8, &lA[rb * 64]);
            async_ld16(xn + (size_t)(gcol0 + r) * DIM + kc * 64 + fch * 8, &lB[rb * 64]);
        }
        __syncthreads();
        #pragma unroll
        for (int s = 0; s < 2; ++s) {
            bf16x8 af[4], bfr[4];
            #pragma unroll
            for (int i = 0; i < 4; ++i) {
                int ra = wr * 64 + i * 16 + m;
                af[i]  = *(const bf16x8*)&lA[ra * 64 + (((s * 4 + q) ^ (ra & 7)) * 8)];
                int rb2 = wc * 64 + i * 16 + m;
                bfr[i] = *(const bf16x8*)&lB[rb2 * 64 + (((s * 4 + q) ^ (rb2 & 7)) * 8)];
            }
            #pragma unroll
            for (int i = 0; i < 4; ++i)
                #pragma unroll
                for (int j = 0; j < 4; ++j)
                    acc[i][j] = __builtin_amdgcn_mfma_f32_16x16x32_bf16(af[i], bfr[j], acc[i][j], 0, 0, 0);
        }
        __syncthreads();
    }
    // epilogue: C/D layout col=lane&15, row=quad*4+reg (m89/m91-verified)
    #pragma unroll
    for (int i = 0; i < 4; ++i) {
        #pragma unroll
        for (int j = 0; j < 4; ++j) {
            int c  = gcol0 + wc * 64 + j * 16 + m;            // global col
            int rb = by * 128 + wr * 64 + i * 16 + q * 4;      // local C row base
            ushort bf[4];
            #pragma unroll
            for (int reg = 0; reg < 4; ++reg) bf[reg] = f2bf(acc[i][j][reg]);
            #pragma unroll
            for (int reg = 0; reg < 4; ++reg) {
                int rl  = rb + reg;                            // row in C buffer
                int grw = row0 + rl;                           // global row
                C[(size_t)rl * NROWS + c] = (grw == c) ? (ushort)0xC040 : bf[reg];
            }
            if (TRI && bx != by) {                             // mirrored tile
                us4 pk4 = { bf[0], bf[1], bf[2], bf[3] };      // 4 consecutive rows
                *(us4*)&C[(size_t)c * NROWS + rb] = pk4;       // 8B store
            }
        }
    }
}

// ---------------- select: wave-per-row exact top-20 + BCE ----------------
// keys: monotone-u16(bf16) so integer max == float max; diag pre-filled -3.
__global__ __launch_bounds__(256) void k_select(const ushort* __restrict__ C,
                                                const int* __restrict__ labels,
                                                int row0, float* __restrict__ acc) {
    __shared__ u32 s_surv[4][256];
    __shared__ u32 s_cnt[4];
    int lane = threadIdx.x & 63;
    int wv   = threadIdx.x >> 6;
    int prow = blockIdx.x * 4 + wv;
    int grow = row0 + prow;
    const uint4* rowp = (const uint4*)(C + (size_t)prow * NROWS);

    if (lane == 0) s_cnt[wv] = 0;
    __syncthreads();

    u32 pk[64];
    u16x2 pm = (u16x2)0;
    #pragma unroll
    for (int i = 0; i < 16; ++i) {
        uint4 v = rowp[i * 64 + lane];
        u32 ws4[4] = { v.x, v.y, v.z, v.w };
        #pragma unroll
        for (int j = 0; j < 4; ++j) {
            u32 w = ws4[j];
            // packed monotone map: per-half  k = r ^ (0x8000 | (r>>15)*0x7FFF)
            u32 k = w ^ (0x80008000u | (((w >> 15) & 0x10001u) * 0x7FFFu));
            pk[i * 4 + j] = k;
            union { u32 u; u16x2 v2; } cv; cv.u = k;
            pm = __builtin_elementwise_max(pm, cv.v2);
        }
    }
    u32 lmax = max((u32)pm.x, (u32)pm.y);

    // T = 20th-largest of the 64 lane maxima: valid lower bound on true 20th.
    u32 cur = lmax, T = 1;
    for (int r = 0; r < KSEL; ++r) {
        u32 w = cur;
        #pragma unroll
        for (int off = 32; off; off >>= 1) w = max(w, __shfl_xor(w, off));
        T = w;
        cur = (cur == w) ? 0u : cur;
    }
    if (T == 0) T = 1;

    // compact survivors (>= T) into LDS; expected ~25 per row
    #pragma unroll
    for (int p = 0; p < 64; ++p) {
        u32 k   = pk[p];
        u32 klo = k & 0xFFFFu, khi = k >> 16;
        u32 wid = (((u32)(p >> 2)) * 64u + (u32)lane) * 4u + (u32)(p & 3);
        if (klo >= T) {
            u32 pos = atomicAdd(&s_cnt[wv], 1u);
            if (pos < 256u) s_surv[wv][pos] = (klo << 16) | (2u * wid);
        }
        if (khi >= T) {
            u32 pos = atomicAdd(&s_cnt[wv], 1u);
            if (pos < 256u) s_surv[wv][pos] = (khi << 16) | (2u * wid + 1u);
        }
    }
    __syncthreads();
    u32 cnt = min(s_cnt[wv], 256u);
    u32 g[4];
    #pragma unroll
    for (int j = 0; j < 4; ++j) {
        u32 idx = (u32)lane + (u32)j * 64u;
        g[j] = (idx < cnt) ? s_surv[wv][idx] : 0u;
    }

    int mylab = labels[grow];
    float loss = 0.0f;
    for (int r = 0; r < KSEL; ++r) {
        u32 w = max(max(g[0], g[1]), max(g[2], g[3]));
        #pragma unroll
        for (int off = 32; off; off >>= 1) w = max(w, __shfl_xor(w, off));
        #pragma unroll
        for (int j = 0; j < 4; ++j) g[j] = (g[j] == w) ? 0u : g[j];  // col makes keys unique
        if (lane == 0) {
            u32 mono = w >> 16, col = w & 0xFFFFu;
            u32 raw  = (mono & 0x8000u) ? (mono ^ 0x8000u) : (mono ^ 0xFFFFu);
            float v  = __uint_as_float(raw << 16);
            float p  = (v + 1.0f) * 0.5f;
            bool t   = (labels[col] == mylab);
            float term = t ? fmaxf(logf(p), -100.0f) : fmaxf(log1pf(-p), -100.0f);
            loss -= term;
        }
    }
    if (lane == 0) atomicAdd(acc, loss);
}

__global__ void k_final(const float* __restrict__ acc, float* __restrict__ out) {
    out[0] = acc[0] * (1.0f / (float)(NROWS * KSEL));
}

extern "C" void kernel_launch(void* const* d_in, const int* in_sizes, int n_in,
                              void* d_out, int out_size, void* d_ws, size_t ws_size,
                              hipStream_t stream) {
    const float* batch  = (const float*)d_in[0];
    const int*   labels = (const int*)d_in[1];

    float*  accp = (float*)d_ws;
    ushort* xn   = (ushort*)((char*)d_ws + 256);
    ushort* C    = xn + (size_t)NROWS * DIM;

    size_t need_full = 256 + (size_t)NROWS * DIM * 2 + (size_t)NROWS * NROWS * 2;

    hipMemsetAsync(accp, 0, sizeof(float), stream);
    k_norm<<<NROWS / 4, 256, 0, stream>>>(batch, xn);

    if (ws_size >= need_full) {
        // full symmetric path: 2080 lower-triangle blocks, one select pass
        k_gemm<true><<<dim3(64 * 65 / 2), 256, 0, stream>>>(xn, C, 0);
        k_select<<<NROWS / 4, 256, 0, stream>>>(C, labels, 0, accp);
    } else {
        // fallback: panel path (24 MB of ws)
        for (int p = 0; p < NROWS / PANEL; ++p) {
            k_gemm<false><<<dim3(64, PANEL / 128), 256, 0, stream>>>(xn, C, p * PANEL);
            k_select<<<PANEL / 4, 256, 0, stream>>>(C, labels, p * PANEL, accp);
        }
    }
    k_final<<<1, 1, 0, stream>>>(accp, (float*)d_out);
}